// Round 1
// baseline (260.468 us; speedup 1.0000x reference)
//
#include <hip/hip_runtime.h>
#include <hip/hip_bf16.h>

// Problem constants (from reference setup_inputs)
constexpr int B_ = 2, T_ = 4096, D_ = 1024, H_ = 8, HD_ = 128, L_ = 5;
constexpr int M_ = B_ * T_;   // 8192 GEMM rows
constexpr int K_ = D_;        // 1024
constexpr int N_ = D_;        // 1024
constexpr int TB_ = 64;       // attention: t-rows per block
constexpr int NSMAX_ = 96;    // attention: max strip rows (supports dil<=8)

// 8-phase GEMM geometry (m201 template: 256^2 tile, BK=64, 8 waves)
constexpr int BM_ = 256, BN_ = 256, BKG_ = 64;
constexpr int NT_ = K_ / BKG_;        // 16 K-tiles
constexpr int TILEG_ = BM_ * BKG_;    // 16384 elems per buffer per matrix

typedef __attribute__((ext_vector_type(8))) __bf16 bf16x8;
typedef __attribute__((ext_vector_type(4))) float f32x4;

__device__ __constant__ int c_srck[8]  = {0, 1, 2, 3, 4, 5, 6, 6};
__device__ __constant__ int c_shift[8] = {0, 0, 0, 0, -2, -1, 1, 2};

__device__ __forceinline__ void gload_lds16(const void* g, void* l) {
    __builtin_amdgcn_global_load_lds(
        (__attribute__((address_space(1))) void*)g,
        (__attribute__((address_space(3))) void*)l, 16, 0, 0);
}

// ---------------------------------------------------------------------------
// f32 -> bf16 bulk convert: grid.y = 0..2 selects (query,Wq)/(key,Wk)/(value,Wv)
// blockIdx.x < 4096 -> input tensor (8M elems); else weight (1M elems).
// ---------------------------------------------------------------------------
__global__ __launch_bounds__(256) void cvt_kernel(
    const float* __restrict__ q,  const float* __restrict__ k,  const float* __restrict__ v,
    const float* __restrict__ wq, const float* __restrict__ wk, const float* __restrict__ wv,
    __hip_bfloat16* __restrict__ qb,  __hip_bfloat16* __restrict__ kb,  __hip_bfloat16* __restrict__ vb,
    __hip_bfloat16* __restrict__ wqb, __hip_bfloat16* __restrict__ wkb, __hip_bfloat16* __restrict__ wvb)
{
    const int y = blockIdx.y;
    const float* src;
    __hip_bfloat16* dst;
    size_t idx;
    if (blockIdx.x < 4096) {
        src = (y == 0) ? q : (y == 1) ? k : v;
        dst = (y == 0) ? qb : (y == 1) ? kb : vb;
        idx = ((size_t)blockIdx.x * 256 + threadIdx.x) * 8;
    } else {
        src = (y == 0) ? wq : (y == 1) ? wk : wv;
        dst = (y == 0) ? wqb : (y == 1) ? wkb : wvb;
        idx = ((size_t)(blockIdx.x - 4096) * 256 + threadIdx.x) * 8;
    }
    f32x4 a = *(const f32x4*)(const void*)(src + idx);
    f32x4 b = *(const f32x4*)(const void*)(src + idx + 4);
    bf16x8 o;
#pragma unroll
    for (int e = 0; e < 4; ++e) { o[e] = (__bf16)a[e]; o[e + 4] = (__bf16)b[e]; }
    *(bf16x8*)(void*)(dst + idx) = o;
}

// ---------------------------------------------------------------------------
// 8-phase 256^2 GEMM (T2 swizzle + T3/T4 counted-vmcnt + T5 setprio).
// y = x @ W^T + b; x:[M,K] bf16, W:[N,K] bf16, bias f32, C bf16.
// 512 threads = 8 waves (2M x 4N), per-wave output 128x64 (acc[8][4]).
// Double-buffered LDS 128 KiB; staging runs 1.5 K-tiles ahead; vmcnt(4)
// at each tile boundary keeps 2 half-tiles in flight across barriers.
// Stage order per tile t: ph1 A1(t+1)->nbuf, ph2 B1(t+1)->nbuf,
// ph3 B0(t+2)->buf (all B reads of buf done by ph2 barrier),
// ph4 A0(t+2)->buf (all A reads of buf done by ph3 barrier).
// XOR swizzle chunk^=row&7: inverse-swizzled global source (linear
// global_load_lds dest, rule 21) + swizzled ds_read address.
// ---------------------------------------------------------------------------
__global__ __launch_bounds__(512, 2) void qkv_gemm_8ph(
    const __hip_bfloat16* __restrict__ qb,
    const __hip_bfloat16* __restrict__ kb,
    const __hip_bfloat16* __restrict__ vb,
    const __hip_bfloat16* __restrict__ wqb,
    const __hip_bfloat16* __restrict__ wkb,
    const __hip_bfloat16* __restrict__ wvb,
    const float* __restrict__ bq,
    const float* __restrict__ bk,
    const float* __restrict__ bv,
    __hip_bfloat16* __restrict__ qout,
    __hip_bfloat16* __restrict__ kout,
    __hip_bfloat16* __restrict__ vout)
{
    const int z = blockIdx.z;
    const __hip_bfloat16* A = (z == 0) ? qb  : (z == 1) ? kb  : vb;
    const __hip_bfloat16* W = (z == 0) ? wqb : (z == 1) ? wkb : wvb;
    const float* bias       = (z == 0) ? bq  : (z == 1) ? bk  : bv;
    __hip_bfloat16* C       = (z == 0) ? qout : (z == 1) ? kout : vout;

    __shared__ __align__(16) __hip_bfloat16 As[2][TILEG_];   // 64 KB
    __shared__ __align__(16) __hip_bfloat16 Bs[2][TILEG_];   // 64 KB

    const int tid  = threadIdx.x;
    const int wave = tid >> 6;
    const int lane = tid & 63;
    const int m0 = blockIdx.x * BM_;
    const int n0 = blockIdx.y * BN_;
    const int wm = (wave >> 2) * 128;   // wave M offset: 0 / 128
    const int wn = (wave & 3) * 64;     // wave N offset: 0/64/128/192

    f32x4 acc[8][4];
#pragma unroll
    for (int i = 0; i < 8; ++i)
#pragma unroll
        for (int j = 0; j < 4; ++j) acc[i][j] = (f32x4){0.f, 0.f, 0.f, 0.f};

    // --- staging geometry: thread covers one 16B chunk per load.
    // srow = tid>>3 (0..63); half-tile = 128 rows = 2 load rounds (r=0,1).
    // Source col is XOR-pre-swizzled so the LINEAR LDS dest holds the
    // swizzled layout.
    const int srow = tid >> 3;
    const int sch  = (tid & 7) ^ (srow & 7);
    const __hip_bfloat16* aSrc = A + (size_t)(m0 + srow) * K_ + sch * 8;
    const __hip_bfloat16* bSrc = W + (size_t)(n0 + srow) * K_ + sch * 8;
    const int wdst = wave * 512;   // wave-uniform LDS base (elems) per round

    auto stageA = [&](int buf, int h, int t) {
        const __hip_bfloat16* s = aSrc + (size_t)h * (128 * K_) + t * BKG_;
        __hip_bfloat16* d = &As[buf][h * 8192 + wdst];
        gload_lds16(s, d);
        gload_lds16(s + (size_t)64 * K_, d + 4096);
    };
    auto stageB = [&](int buf, int h, int t) {
        const __hip_bfloat16* s = bSrc + (size_t)h * (128 * K_) + t * BKG_;
        __hip_bfloat16* d = &Bs[buf][h * 8192 + wdst];
        gload_lds16(s, d);
        gload_lds16(s + (size_t)64 * K_, d + 4096);
    };

    // --- fragment read geometry (swizzled read addresses).
    // row = base+fr, k-chunk = kk*4 + (lane>>4); swz chunk ^= fr&7.
    // Each 16-lane b128 group then covers all 32 banks exactly 2x (free).
    const int fr = lane & 15;
    const int fx = lane >> 4;
    const int c0 = ((0 + fx) ^ (fr & 7)) * 8;   // kk=0 chunk (elems)
    const int c1 = ((4 + fx) ^ (fr & 7)) * 8;   // kk=1 chunk (elems)

    bf16x8 a[4][2], b0[2][2], b1[2][2];

    auto lda = [&](int buf, int mh) {
        const __hip_bfloat16* p = &As[buf][(wm + mh * 64 + fr) * 64];
#pragma unroll
        for (int mi = 0; mi < 4; ++mi) {
            a[mi][0] = *(const bf16x8*)(const void*)(p + mi * 1024 + c0);
            a[mi][1] = *(const bf16x8*)(const void*)(p + mi * 1024 + c1);
        }
    };
    auto ldb = [&](bf16x8 (&bf)[2][2], int buf, int nh) {
        const __hip_bfloat16* p = &Bs[buf][(wn + nh * 32 + fr) * 64];
#pragma unroll
        for (int nj = 0; nj < 2; ++nj) {
            bf[nj][0] = *(const bf16x8*)(const void*)(p + nj * 1024 + c0);
            bf[nj][1] = *(const bf16x8*)(const void*)(p + nj * 1024 + c1);
        }
    };
    auto mfma_q = [&](int mh, int nh, bf16x8 (&bf)[2][2]) {
#pragma unroll
        for (int kk = 0; kk < 2; ++kk)
#pragma unroll
            for (int mi = 0; mi < 4; ++mi)
#pragma unroll
                for (int nj = 0; nj < 2; ++nj)
                    acc[mh * 4 + mi][nh * 2 + nj] =
                        __builtin_amdgcn_mfma_f32_16x16x32_bf16(
                            a[mi][kk], bf[nj][kk],
                            acc[mh * 4 + mi][nh * 2 + nj], 0, 0, 0);
    };

    // --- prologue: tile0 complete + tile1 {B0,A0} issued (newest 4 in flight)
    stageA(0, 0, 0); stageB(0, 0, 0);
    stageA(0, 1, 0); stageB(0, 1, 0);
    stageB(1, 0, 1); stageA(1, 0, 1);
    asm volatile("s_waitcnt vmcnt(4)" ::: "memory");
    __builtin_amdgcn_s_barrier();

#pragma unroll 1
    for (int t = 0; t < NT_; ++t) {
        const int buf = t & 1, nbuf = buf ^ 1;

        // phase 1: read A(mh0)+B(nh0) | stage A1(t+1) | quadrant (0,0)
        lda(buf, 0); ldb(b0, buf, 0);
        if (t + 1 < NT_) stageA(nbuf, 1, t + 1);
        __builtin_amdgcn_s_barrier();
        asm volatile("s_waitcnt lgkmcnt(0)" ::: "memory");
        __builtin_amdgcn_sched_barrier(0);
        __builtin_amdgcn_s_setprio(1);
        mfma_q(0, 0, b0);
        __builtin_amdgcn_s_setprio(0);
        __builtin_amdgcn_s_barrier();

        // phase 2: read B(nh1) | stage B1(t+1) | quadrant (0,1)
        ldb(b1, buf, 1);
        if (t + 1 < NT_) stageB(nbuf, 1, t + 1);
        __builtin_amdgcn_s_barrier();
        asm volatile("s_waitcnt lgkmcnt(0)" ::: "memory");
        __builtin_amdgcn_sched_barrier(0);
        __builtin_amdgcn_s_setprio(1);
        mfma_q(0, 1, b1);
        __builtin_amdgcn_s_setprio(0);
        __builtin_amdgcn_s_barrier();

        // phase 3: read A(mh1) | stage B0(t+2) into buf | quadrant (1,1)
        lda(buf, 1);
        if (t + 2 < NT_) stageB(buf, 0, t + 2);
        __builtin_amdgcn_s_barrier();
        asm volatile("s_waitcnt lgkmcnt(0)" ::: "memory");
        __builtin_amdgcn_sched_barrier(0);
        __builtin_amdgcn_s_setprio(1);
        mfma_q(1, 1, b1);
        __builtin_amdgcn_s_setprio(0);
        __builtin_amdgcn_s_barrier();

        // phase 4: stage A0(t+2) into buf | quadrant (1,0) from registers |
        // counted-vmcnt tile boundary (never 0 in steady state)
        if (t + 2 < NT_) stageA(buf, 0, t + 2);
        __builtin_amdgcn_s_barrier();
        __builtin_amdgcn_s_setprio(1);
        mfma_q(1, 0, b0);
        __builtin_amdgcn_s_setprio(0);
        if (t < NT_ - 2) asm volatile("s_waitcnt vmcnt(4)" ::: "memory");
        else             asm volatile("s_waitcnt vmcnt(0)" ::: "memory");
        __builtin_amdgcn_s_barrier();
    }

    // epilogue: C/D layout col=lane&15, row=(lane>>4)*4+r (m89)
    const int col_l = lane & 15;
    const int row_l = (lane >> 4) * 4;
#pragma unroll
    for (int J = 0; J < 4; ++J) {
        const int n = n0 + wn + J * 16 + col_l;
        const float bval = bias[n];
#pragma unroll
        for (int I = 0; I < 8; ++I) {
            const int m = m0 + wm + I * 16 + row_l;
#pragma unroll
            for (int r = 0; r < 4; ++r)
                C[(size_t)(m + r) * N_ + n] = __float2bfloat16(acc[I][J][r] + bval);
        }
    }
}

// ---------------------------------------------------------------------------
// Fallback GEMM (R3 version): f32 staging with XOR swizzle. Used only if
// ws_size is too small for the bf16 pre-convert buffers.
// ---------------------------------------------------------------------------
__global__ __launch_bounds__(256) void qkv_gemm_f32(
    const float* __restrict__ query,
    const float* __restrict__ key,
    const float* __restrict__ value,
    const float* __restrict__ Wq,
    const float* __restrict__ bq,
    const float* __restrict__ Wk,
    const float* __restrict__ bk,
    const float* __restrict__ Wv,
    const float* __restrict__ bv,
    __hip_bfloat16* __restrict__ qout,
    __hip_bfloat16* __restrict__ kout,
    __hip_bfloat16* __restrict__ vout)
{
    const int z = blockIdx.z;
    const float* A    = (z == 0) ? query : (z == 1) ? key : value;
    const float* W    = (z == 0) ? Wq    : (z == 1) ? Wk  : Wv;
    const float* bias = (z == 0) ? bq    : (z == 1) ? bk  : bv;
    __hip_bfloat16* C = (z == 0) ? qout  : (z == 1) ? kout : vout;

    __shared__ __align__(16) float As[128 * 32];
    __shared__ __align__(16) float Bs[128 * 32];

    const int tid  = threadIdx.x;
    const int wave = tid >> 6;
    const int lane = tid & 63;
    const int m0 = blockIdx.x * 128;
    const int n0 = blockIdx.y * 128;
    const int wm = (wave >> 1) * 64;
    const int wn = (wave & 1) * 64;

    f32x4 acc[4][4];
#pragma unroll
    for (int i = 0; i < 4; ++i)
#pragma unroll
        for (int j = 0; j < 4; ++j)
            acc[i][j] = (f32x4){0.f, 0.f, 0.f, 0.f};

    const int srow = lane >> 3;
    const int lcg  = (lane & 7) ^ srow;
    const int gcol = lcg * 4;

    const int fr  = lane & 15;
    const int r7  = fr & 7;
    const int cgA = (lane >> 4) * 2;
    const int pcg0 = (cgA)     ^ r7;
    const int pcg1 = (cgA ^ 1) ^ r7;

    for (int k0 = 0; k0 < K_; k0 += 32) {
#pragma unroll
        for (int r = 0; r < 4; ++r) {
            const int issue = wave + r * 4;
            const int row = issue * 8 + srow;
            gload_lds16(A + (size_t)(m0 + row) * K_ + k0 + gcol,
                        (void*)(As + issue * 256));
            gload_lds16(W + (size_t)(n0 + row) * K_ + k0 + gcol,
                        (void*)(Bs + issue * 256));
        }
        __syncthreads();

        bf16x8 af[4], bf[4];
#pragma unroll
        for (int i = 0; i < 4; ++i) {
            const float* ap = As + (wm + i * 16 + fr) * 32;
            f32x4 a0 = *(const f32x4*)(const void*)(ap + pcg0 * 4);
            f32x4 a1 = *(const f32x4*)(const void*)(ap + pcg1 * 4);
            const float* bp = Bs + (wn + i * 16 + fr) * 32;
            f32x4 b0 = *(const f32x4*)(const void*)(bp + pcg0 * 4);
            f32x4 b1 = *(const f32x4*)(const void*)(bp + pcg1 * 4);
#pragma unroll
            for (int e = 0; e < 4; ++e) {
                af[i][e]     = (__bf16)a0[e];
                af[i][e + 4] = (__bf16)a1[e];
                bf[i][e]     = (__bf16)b0[e];
                bf[i][e + 4] = (__bf16)b1[e];
            }
        }
#pragma unroll
        for (int i = 0; i < 4; ++i)
#pragma unroll
            for (int j = 0; j < 4; ++j)
                acc[i][j] = __builtin_amdgcn_mfma_f32_16x16x32_bf16(
                    af[i], bf[j], acc[i][j], 0, 0, 0);
        __syncthreads();
    }

    const int col_l = lane & 15;
    const int row_l = (lane >> 4) * 4;
#pragma unroll
    for (int j = 0; j < 4; ++j) {
        const int n = n0 + wn + j * 16 + col_l;
        const float bval = bias[n];
#pragma unroll
        for (int i = 0; i < 4; ++i) {
            const int m = m0 + wm + i * 16 + row_l;
#pragma unroll
            for (int r = 0; r < 4; ++r)
                C[(size_t)(m + r) * N_ + n] = __float2bfloat16(acc[i][j][r] + bval);
        }
    }
}

// ---------------------------------------------------------------------------
// Attention v2: one block per (b, h, 64-t strip). K/V strips staged in LDS
// (16B XOR swizzle), Er transposed in LDS. 4 lanes per row x 32 dims/lane.
// orig(t,j) = t + (shift+j-2)*dil, valid iff 0<=orig<T (mod-Tp wraps are
// exactly the invalid/masked slots). OOB strip rows zero-filled (no NaN).
// ---------------------------------------------------------------------------
__global__ __launch_bounds__(256) void attn_kernel(
    const __hip_bfloat16* __restrict__ qp,
    const __hip_bfloat16* __restrict__ kp,
    const __hip_bfloat16* __restrict__ vp,
    const float* __restrict__ Er,
    const int* __restrict__ layer_p,
    float* __restrict__ out,
    float* __restrict__ attn_out)
{
    const int dil = 1 << (*layer_p);
    int NS = TB_ + 4 * dil;
    if (NS > NSMAX_) NS = NSMAX_;     // geometry beyond layer=3 unsupported

    const int tid = threadIdx.x;
    const int t0 = blockIdx.x * TB_;
    const int h  = blockIdx.y;
    const int b  = blockIdx.z;
    const int shift = c_shift[h];
    const int srck  = c_srck[h];
    const int off_lo = (shift - 2) * dil;

    __shared__ __align__(16) __hip_bfloat16 Ks[NSMAX_ * 128];  // 24 KB
    __shared__ __align__(16) __hip_bfloat16 Vs[NSMAX_ * 128];  // 24 KB
    __shared__ __align__(16) float ErT[5][128];                // 2.5 KB

    // stage ErT[j][d] = Er[h, d, j] (source contiguous, coalesced)
    for (int i = tid; i < 640; i += 256) {
        const int d = i / 5, j = i - d * 5;
        ErT[j][d] = Er[(size_t)h * 640 + i];
    }

    // stage K/V strips: 16 rows per pass, lane sc covers 16B chunk sc
    const int sr = tid >> 4;
    const int sc = tid & 15;
    for (int i0 = 0; i0 < NS; i0 += 16) {
        const int i = i0 + sr;
        if (i < NS) {
            const int r = t0 + off_lo + i;
            bf16x8 kv8 = (bf16x8){0, 0, 0, 0, 0, 0, 0, 0};
            bf16x8 vv8 = (bf16x8){0, 0, 0, 0, 0, 0, 0, 0};
            if (r >= 0 && r < T_) {
                kv8 = *(const bf16x8*)(const void*)(
                    kp + (size_t)(b * T_ + r) * D_ + srck * HD_ + sc * 8);
                vv8 = *(const bf16x8*)(const void*)(
                    vp + (size_t)(b * T_ + r) * D_ + h * HD_ + sc * 8);
            }
            const int pc = sc ^ (i & 3);
            *(bf16x8*)(void*)(Ks + i * 128 + pc * 8) = kv8;
            *(bf16x8*)(void*)(Vs + i * 128 + pc * 8) = vv8;
        }
    }
    __syncthreads();

    // compute: row t = t0 + tid/4; lane quarter ld = tid%4 owns dims ld*32..+31
    const int lr = tid >> 2;
    const int ld = tid & 3;
    const int t  = t0 + lr;
    const size_t qoff = (size_t)(b * T_ + t) * D_ + h * HD_ + ld * 32;

    float qf[32];
#pragma unroll
    for (int c = 0; c < 4; ++c) {
        bf16x8 qv = *(const bf16x8*)(const void*)(qp + qoff + c * 8);
#pragma unroll
        for (int e = 0; e < 8; ++e) qf[c * 8 + e] = (float)qv[e];
    }

    float lg[5];
    bool  valid[5];
    int   irow[5];
#pragma unroll
    for (int j = 0; j < 5; ++j) {
        const int i = lr + j * dil;          // strip row
        irow[j] = i;
        const int orig = t + (shift + j - 2) * dil;
        valid[j] = (orig >= 0) && (orig < T_);

        float s = 0.f;
#pragma unroll
        for (int c = 0; c < 4; ++c) {
            const int pc = (ld * 4 + c) ^ (i & 3);
            bf16x8 kk = *(const bf16x8*)(const void*)(Ks + i * 128 + pc * 8);
#pragma unroll
            for (int e = 0; e < 8; ++e) s += qf[c * 8 + e] * (float)kk[e];
        }
        if (!valid[j]) s = 0.f;              // mirror qk==0 masking base
#pragma unroll
        for (int c = 0; c < 8; ++c) {
            f32x4 ev = *(const f32x4*)(const void*)(&ErT[j][ld * 32 + c * 4]);
#pragma unroll
            for (int e = 0; e < 4; ++e) s += qf[c * 4 + e] * ev[e];
        }
        s += __shfl_xor(s, 1, 4);
        s += __shfl_xor(s, 2, 4);
        lg[j] = valid[j] ? s * 0.08838834764831845f : -INFINITY;
    }

    float mx = lg[0];
#pragma unroll
    for (int j = 1; j < 5; ++j) mx = fmaxf(mx, lg[j]);
    float w[5], sum = 0.f;
#pragma unroll
    for (int j = 0; j < 5; ++j) {
        w[j] = valid[j] ? __expf(lg[j] - mx) : 0.f;
        sum += w[j];
    }
    const float inv = 1.f / sum;
#pragma unroll
    for (int j = 0; j < 5; ++j) w[j] *= inv;

    float o[32];
#pragma unroll
    for (int m = 0; m < 32; ++m) o[m] = 0.f;
#pragma unroll
    for (int j = 0; j < 5; ++j) {
        const int i = irow[j];
#pragma unroll
        for (int c = 0; c < 4; ++c) {
            const int pc = (ld * 4 + c) ^ (i & 3);
            bf16x8 vv = *(const bf16x8*)(const void*)(Vs + i * 128 + pc * 8);
#pragma unroll
            for (int e = 0; e < 8; ++e) o[c * 8 + e] += w[j] * (float)vv[e];
        }
    }

#pragma unroll
    for (int c = 0; c < 8; ++c) {
        f32x4 ov = (f32x4){o[c * 4], o[c * 4 + 1], o[c * 4 + 2], o[c * 4 + 3]};
        *(f32x4*)(void*)(out + qoff + c * 4) = ov;
    }

    const size_t abase = ((size_t)(b * H_ + h) * T_ + t) * L_;
    attn_out[abase + ld] = w[ld];
    if (ld == 0) attn_out[abase + 4] = w[4];
}

// ---------------------------------------------------------------------------
extern "C" void kernel_launch(void* const* d_in, const int* in_sizes, int n_in,
                              void* d_out, int out_size, void* d_ws, size_t ws_size,
                              hipStream_t stream) {
    const float* query = (const float*)d_in[0];
    const float* key   = (const float*)d_in[1];
    const float* value = (const float*)d_in[2];
    const float* Wq    = (const float*)d_in[3];
    const float* bq    = (const float*)d_in[4];
    const float* Wk    = (const float*)d_in[5];
    const float* bk    = (const float*)d_in[6];
    const float* Wv    = (const float*)d_in[7];
    const float* bv    = (const float*)d_in[8];
    const float* Er    = (const float*)d_in[9];
    const int*   layer = (const int*)d_in[10];

    float* out  = (float*)d_out;
    float* attn = out + (size_t)B_ * T_ * D_;

    const size_t SA = (size_t)M_ * K_;       // 8M elems
    const size_t SW = (size_t)N_ * K_;       // 1M elems
    const size_t SP = (size_t)M_ * N_;       // 8M elems
    const size_t need = (3 * SA + 3 * SW + 3 * SP) * sizeof(__hip_bfloat16);

    char* ws = (char*)d_ws;
    if (ws_size >= need) {
        __hip_bfloat16* qb  = (__hip_bfloat16*)ws;
        __hip_bfloat16* kb  = qb + SA;
        __hip_bfloat16* vb  = kb + SA;
        __hip_bfloat16* wqb = vb + SA;
        __hip_bfloat16* wkb = wqb + SW;
        __hip_bfloat16* wvb = wkb + SW;
        __hip_bfloat16* qp  = wvb + SW;
        __hip_bfloat16* kp  = qp + SP;
        __hip_bfloat16* vp  = kp + SP;

        cvt_kernel<<<dim3(4608, 3), 256, 0, stream>>>(
            query, key, value, Wq, Wk, Wv, qb, kb, vb, wqb, wkb, wvb);

        qkv_gemm_8ph<<<dim3(M_ / BM_, N_ / BN_, 3), 512, 0, stream>>>(
            qb, kb, vb, wqb, wkb, wvb, bq, bk, bv, qp, kp, vp);

        attn_kernel<<<dim3(T_ / TB_, H_, B_), 256, 0, stream>>>(
            qp, kp, vp, Er, layer, out, attn);
    } else {
        __hip_bfloat16* qp = (__hip_bfloat16*)ws;
        __hip_bfloat16* kp = qp + SP;
        __hip_bfloat16* vp = kp + SP;

        qkv_gemm_f32<<<dim3(M_ / 128, N_ / 128, 3), 256, 0, stream>>>(
            query, key, value, Wq, bq, Wk, bk, Wv, bv, qp, kp, vp);

        attn_kernel<<<dim3(T_ / TB_, H_, B_), 256, 0, stream>>>(
            qp, kp, vp, Er, layer, out, attn);
    }
}